// Round 2
// baseline (33.384 us; speedup 1.0000x reference)
//
#include <hip/hip_runtime.h>

// x,y: [B=8, T=2048, C=1024] fp32.
// -mean(einsum('itj,itl->ijl', x, y)) ==
//   -(1/(B*C*C)) * sum_{rows} rowsum(x_row) * rowsum(y_row)
// Per wave:  acc_lane += sx_lane * Sy   (only Sy needs the per-row butterfly;
// sum over lanes of acc at the end equals sum of Sx*Sy).
#define N_ROWS 16384
#define N_C    1024
#define DENOM  (8.0 * 1024.0 * 1024.0)  // B*C*C

#define THREADS 256
#define BLOCKS  2048                      // 8192 waves -> 2 rows per wave
#define N_PART  (BLOCKS * THREADS / 64)   // 8192 float partials

__global__ __launch_bounds__(THREADS)
void corr_partial(const float* __restrict__ x,
                  const float* __restrict__ y,
                  float* __restrict__ partials) {
    const int lane = threadIdx.x & 63;
    const int wave = (blockIdx.x * THREADS + threadIdx.x) >> 6;   // 0..8191

    const size_t base0 = (size_t)(2 * wave) * N_C;                // 2 rows/wave
    const float4* x0 = (const float4*)(x + base0);
    const float4* y0 = (const float4*)(y + base0);
    const float4* x1 = (const float4*)(x + base0 + N_C);
    const float4* y1 = (const float4*)(y + base0 + N_C);

    // Issue all 16 coalesced 16B loads up front (ILP; no dependent use yet).
    float4 a0[4], b0[4], a1[4], b1[4];
    #pragma unroll
    for (int k = 0; k < 4; ++k) {
        a0[k] = x0[lane + 64 * k];
        b0[k] = y0[lane + 64 * k];
        a1[k] = x1[lane + 64 * k];
        b1[k] = y1[lane + 64 * k];
    }

    float sx0 = 0.f, sy0 = 0.f, sx1 = 0.f, sy1 = 0.f;
    #pragma unroll
    for (int k = 0; k < 4; ++k) {
        sx0 += (a0[k].x + a0[k].y) + (a0[k].z + a0[k].w);
        sy0 += (b0[k].x + b0[k].y) + (b0[k].z + b0[k].w);
        sx1 += (a1[k].x + a1[k].y) + (a1[k].z + a1[k].w);
        sy1 += (b1[k].x + b1[k].y) + (b1[k].z + b1[k].w);
    }

    // Butterfly-reduce ONLY the y sums; the two rows' chains are independent
    // and interleave (6-deep latency total instead of 24-deep).
    #pragma unroll
    for (int off = 32; off > 0; off >>= 1) {
        sy0 += __shfl_xor(sy0, off, 64);
        sy1 += __shfl_xor(sy1, off, 64);
    }

    float acc = sx0 * sy0 + sx1 * sy1;   // lane-partial of Sx0*Sy0 + Sx1*Sy1
    #pragma unroll
    for (int off = 32; off > 0; off >>= 1)
        acc += __shfl_xor(acc, off, 64); // once per wave, not once per row
    if (lane == 0) partials[wave] = acc;
}

__global__ __launch_bounds__(256)
void corr_final_reduce(const float* __restrict__ partials,
                       float* __restrict__ out) {
    __shared__ double sdata[256];
    double acc = 0.0;
    for (int i = threadIdx.x; i < N_PART; i += 256) acc += (double)partials[i];
    sdata[threadIdx.x] = acc;
    __syncthreads();
    for (int s = 128; s > 0; s >>= 1) {
        if (threadIdx.x < s) sdata[threadIdx.x] += sdata[threadIdx.x + s];
        __syncthreads();
    }
    if (threadIdx.x == 0) out[0] = (float)(-sdata[0] / DENOM);
}

extern "C" void kernel_launch(void* const* d_in, const int* in_sizes, int n_in,
                              void* d_out, int out_size, void* d_ws, size_t ws_size,
                              hipStream_t stream) {
    const float* x = (const float*)d_in[0];
    const float* y = (const float*)d_in[1];
    float* out = (float*)d_out;
    float* partials = (float*)d_ws;   // N_PART * 4 = 32 KiB scratch

    corr_partial<<<BLOCKS, THREADS, 0, stream>>>(x, y, partials);
    corr_final_reduce<<<1, 256, 0, stream>>>(partials, out);
}

// Round 3
// 31.462 us; speedup vs baseline: 1.0611x; 1.0611x over previous
//
#include <hip/hip_runtime.h>

// x,y: [B=8, T=2048, C=1024] fp32.
// -mean(einsum('itj,itl->ijl', x, y)) ==
//   -(1/(B*C*C)) * sum_{rows} rowsum(x_row) * rowsum(y_row)
// Per row: acc_lane += sx_lane * Sy  (butterfly only the y sum; the lane-sum
// of acc at wave end equals sum of Sx*Sy over the wave's rows).
#define N_ROWS 16384
#define N_C    1024
#define DENOM  (8.0 * 1024.0 * 1024.0)  // B*C*C

#define THREADS 256
#define BLOCKS  1024
#define WAVES   (BLOCKS * THREADS / 64)   // 4096 waves
#define ROWS_PER_WAVE (N_ROWS / WAVES)    // 4

__global__ __launch_bounds__(THREADS)
void corr_partial(const float* __restrict__ x,
                  const float* __restrict__ y,
                  float* __restrict__ partials) {
    const int lane = threadIdx.x & 63;
    const int wave = (blockIdx.x * THREADS + threadIdx.x) >> 6;   // 0..4095

    // Wave owns 4 consecutive rows: contiguous 16 KB per input.
    const size_t row0 = (size_t)wave * ROWS_PER_WAVE;
    const float4* xb = (const float4*)(x + row0 * N_C);
    const float4* yb = (const float4*)(y + row0 * N_C);
    const int RQ = N_C / 4;   // 256 float4 per row

    // Software pipeline: buf[0]/buf[1] alternate; next row's 8 loads are
    // issued BEFORE the current row's reduction (shuffles are lgkmcnt,
    // loads are vmcnt -> they overlap). Fully unrolled => static indices.
    float4 cx[2][4], cy[2][4];

    #pragma unroll
    for (int k = 0; k < 4; ++k) {
        cx[0][k] = xb[lane + 64 * k];
        cy[0][k] = yb[lane + 64 * k];
    }

    float acc = 0.f;
    #pragma unroll
    for (int r = 0; r < ROWS_PER_WAVE; ++r) {
        const int cur = r & 1, nxt = cur ^ 1;
        if (r + 1 < ROWS_PER_WAVE) {
            #pragma unroll
            for (int k = 0; k < 4; ++k) {
                cx[nxt][k] = xb[(r + 1) * RQ + lane + 64 * k];
                cy[nxt][k] = yb[(r + 1) * RQ + lane + 64 * k];
            }
        }
        float sx = 0.f, sy = 0.f;
        #pragma unroll
        for (int k = 0; k < 4; ++k) {
            sx += (cx[cur][k].x + cx[cur][k].y) + (cx[cur][k].z + cx[cur][k].w);
            sy += (cy[cur][k].x + cy[cur][k].y) + (cy[cur][k].z + cy[cur][k].w);
        }
        #pragma unroll
        for (int off = 32; off > 0; off >>= 1)
            sy += __shfl_xor(sy, off, 64);
        acc += sx * sy;       // lane-partial; Sy is wave-uniform
    }

    // One wave-wide butterfly at the end.
    #pragma unroll
    for (int off = 32; off > 0; off >>= 1)
        acc += __shfl_xor(acc, off, 64);
    if (lane == 0) partials[wave] = acc;
}

__global__ __launch_bounds__(256)
void corr_final_reduce(const float* __restrict__ partials,
                       float* __restrict__ out) {
    __shared__ double sdata[256];
    double acc = 0.0;
    for (int i = threadIdx.x; i < WAVES; i += 256) acc += (double)partials[i];
    sdata[threadIdx.x] = acc;
    __syncthreads();
    for (int s = 128; s > 0; s >>= 1) {
        if (threadIdx.x < s) sdata[threadIdx.x] += sdata[threadIdx.x + s];
        __syncthreads();
    }
    if (threadIdx.x == 0) out[0] = (float)(-sdata[0] / DENOM);
}

extern "C" void kernel_launch(void* const* d_in, const int* in_sizes, int n_in,
                              void* d_out, int out_size, void* d_ws, size_t ws_size,
                              hipStream_t stream) {
    const float* x = (const float*)d_in[0];
    const float* y = (const float*)d_in[1];
    float* out = (float*)d_out;
    float* partials = (float*)d_ws;   // WAVES * 4 = 16 KiB scratch

    corr_partial<<<BLOCKS, THREADS, 0, stream>>>(x, y, partials);
    corr_final_reduce<<<1, 256, 0, stream>>>(partials, out);
}

// Round 4
// 28.080 us; speedup vs baseline: 1.1889x; 1.1204x over previous
//
#include <hip/hip_runtime.h>

// x,y: [B=8, T=2048, C=1024] fp32.
// -mean(einsum('itj,itl->ijl', x, y)) ==
//   -(1/(B*C*C)) * sum_{rows} rowsum(x_row) * rowsum(y_row)
//
// Key restructure vs prior rounds: the streaming loop has ZERO cross-lane
// ops. Each wave owns 2 rows; lanes keep per-row per-lane float4 partials.
// All 4 wave reductions (sx0,sy0,sx1,sy1) happen ONCE at wave end as
// independent interleaved butterflies (single ~250cy latency tail).
#define N_C    1024
#define DENOM  (8.0 * 1024.0 * 1024.0)  // B*C*C

#define THREADS 256
#define BLOCKS  2048
#define WAVES   (BLOCKS * THREADS / 64)   // 8192 waves, 2 rows each

__global__ __launch_bounds__(THREADS)
void corr_partial(const float* __restrict__ x,
                  const float* __restrict__ y,
                  float* __restrict__ partials) {
    const int lane = threadIdx.x & 63;
    const int wave = (blockIdx.x * THREADS + threadIdx.x) >> 6;   // 0..8191

    const size_t base = (size_t)(2 * wave) * N_C;   // 2 consecutive rows
    const float4* x0 = (const float4*)(x + base);
    const float4* y0 = (const float4*)(y + base);
    const float4* x1 = (const float4*)(x + base + N_C);
    const float4* y1 = (const float4*)(y + base + N_C);

    // Pure streaming: 16 coalesced float4 loads, vector adds, no shuffles.
    float4 ax = {0,0,0,0}, ay = {0,0,0,0}, bx = {0,0,0,0}, by = {0,0,0,0};
    #pragma unroll
    for (int k = 0; k < 4; ++k) {
        float4 vx0 = x0[lane + 64 * k];
        float4 vy0 = y0[lane + 64 * k];
        float4 vx1 = x1[lane + 64 * k];
        float4 vy1 = y1[lane + 64 * k];
        ax.x += vx0.x; ax.y += vx0.y; ax.z += vx0.z; ax.w += vx0.w;
        ay.x += vy0.x; ay.y += vy0.y; ay.z += vy0.z; ay.w += vy0.w;
        bx.x += vx1.x; bx.y += vx1.y; bx.z += vx1.z; bx.w += vx1.w;
        by.x += vy1.x; by.y += vy1.y; by.z += vy1.z; by.w += vy1.w;
    }
    float sx0 = (ax.x + ax.y) + (ax.z + ax.w);
    float sy0 = (ay.x + ay.y) + (ay.z + ay.w);
    float sx1 = (bx.x + bx.y) + (bx.z + bx.w);
    float sy1 = (by.x + by.y) + (by.z + by.w);

    // Four INDEPENDENT 64-lane butterflies, interleaved -> one latency tail.
    #pragma unroll
    for (int off = 32; off > 0; off >>= 1) {
        sx0 += __shfl_xor(sx0, off, 64);
        sy0 += __shfl_xor(sy0, off, 64);
        sx1 += __shfl_xor(sx1, off, 64);
        sy1 += __shfl_xor(sy1, off, 64);
    }
    // All lanes now hold the full row sums (wave-uniform).
    if (lane == 0) partials[wave] = sx0 * sy0 + sx1 * sy1;
}

__global__ __launch_bounds__(1024)
void corr_final_reduce(const float* __restrict__ partials,
                       float* __restrict__ out) {
    __shared__ double sdata[1024];
    double acc = 0.0;
    for (int i = threadIdx.x; i < WAVES; i += 1024) acc += (double)partials[i];
    sdata[threadIdx.x] = acc;
    __syncthreads();
    for (int s = 512; s > 0; s >>= 1) {
        if (threadIdx.x < s) sdata[threadIdx.x] += sdata[threadIdx.x + s];
        __syncthreads();
    }
    if (threadIdx.x == 0) out[0] = (float)(-sdata[0] / DENOM);
}

extern "C" void kernel_launch(void* const* d_in, const int* in_sizes, int n_in,
                              void* d_out, int out_size, void* d_ws, size_t ws_size,
                              hipStream_t stream) {
    const float* x = (const float*)d_in[0];
    const float* y = (const float*)d_in[1];
    float* out = (float*)d_out;
    float* partials = (float*)d_ws;   // WAVES * 4 = 32 KiB scratch

    corr_partial<<<BLOCKS, THREADS, 0, stream>>>(x, y, partials);
    corr_final_reduce<<<1, 1024, 0, stream>>>(partials, out);
}